// Round 3
// baseline (195.012 us; speedup 1.0000x reference)
//
#include <hip/hip_runtime.h>
#include <math.h>

#define PROJ 8192
#define CDIM 512
#define HWPOS 196
#define NBATCH 32
#define KPAD 224            // 7 slabs of 32
#define NSLAB 7
#define NTP 10              // tile pairs bi<=bj over 4x4 grid of 128-col tiles

typedef __attribute__((ext_vector_type(8))) short   short8;
typedef __attribute__((ext_vector_type(4))) float   f32x4;

__device__ __forceinline__ unsigned short f2bf(float f) {
    unsigned u = __float_as_uint(f);
    u += 0x7fff + ((u >> 16) & 1);          // round-to-nearest-even
    return (unsigned short)(u >> 16);
}
__device__ __forceinline__ float bf2f(unsigned short h) {
    return __uint_as_float(((unsigned)h) << 16);
}

// ---------------------------------------------------------------------------
// Kernel 1: extract (h, s) from the dense sketch matrices + zero norm accum.
// ---------------------------------------------------------------------------
__global__ __launch_bounds__(256) void extract_kernel(
    const float* __restrict__ M1, const float* __restrict__ M2,
    int* __restrict__ h1, float* __restrict__ s1,
    int* __restrict__ h2, float* __restrict__ s2,
    float* __restrict__ norm)
{
    const int row = blockIdx.x;
    const float* M = blockIdx.y ? M2 : M1;
    int*   h = blockIdx.y ? h2 : h1;
    float* s = blockIdx.y ? s2 : s1;
    const float* mrow = M + (size_t)row * PROJ;

    if (blockIdx.x == 0 && blockIdx.y == 0 && threadIdx.x < NBATCH)
        norm[threadIdx.x] = 0.0f;

    for (int i = threadIdx.x * 4; i < PROJ; i += 256 * 4) {
        float4 v = *(const float4*)(mrow + i);
        if (v.x != 0.0f) { h[row] = i + 0; s[row] = v.x; }
        if (v.y != 0.0f) { h[row] = i + 1; s[row] = v.y; }
        if (v.z != 0.0f) { h[row] = i + 2; s[row] = v.z; }
        if (v.w != 0.0f) { h[row] = i + 3; s[row] = v.w; }
    }
}

// ---------------------------------------------------------------------------
// Kernel 2: prep — split fp32 x into bf16 hi/lo, transpose to fragment order.
// Output layout (ushort): [b][kslab(7)][cgrp(32)][quad(4)][c16(16)][j(8)]
// i.e. element (c = cgrp*16+c16, k = kslab*32+quad*8+j); k>=196 zero-padded.
// Grid (7, 32), 256 threads.
// ---------------------------------------------------------------------------
__global__ __launch_bounds__(256) void prep_kernel(
    const float* __restrict__ x,
    unsigned short* __restrict__ XThi, unsigned short* __restrict__ XTlo)
{
    const int ks  = blockIdx.x;
    const int bat = blockIdx.y;
    const int tid = threadIdx.x;
    __shared__ float xt[32][513];            // +1 pad breaks bank conflicts

    const float* xb = x + (size_t)bat * HWPOS * CDIM;
    const int k0 = ks * 32;
#pragma unroll
    for (int i = 0; i < 16; ++i) {
        const int idx = i * 1024 + tid * 4;
        const int kr  = idx >> 9;
        const int c   = idx & 511;
        float4 v = make_float4(0.f, 0.f, 0.f, 0.f);
        if (k0 + kr < HWPOS) v = *(const float4*)(xb + (size_t)(k0 + kr) * CDIM + c);
        xt[kr][c+0] = v.x; xt[kr][c+1] = v.y; xt[kr][c+2] = v.z; xt[kr][c+3] = v.w;
    }
    __syncthreads();

    unsigned short* ohi = XThi + ((size_t)bat * NSLAB + ks) * 16384;
    unsigned short* olo = XTlo + ((size_t)bat * NSLAB + ks) * 16384;
#pragma unroll
    for (int i = 0; i < 8; ++i) {
        const int ch   = i * 256 + tid;      // chunk 0..2047, memory order
        const int c16  = ch & 15;
        const int quad = (ch >> 4) & 3;
        const int cgrp = ch >> 6;
        const int c    = cgrp * 16 + c16;
        short8 vh, vl;
#pragma unroll
        for (int j = 0; j < 8; ++j) {
            float f = xt[quad * 8 + j][c];
            unsigned short h = f2bf(f);
            vh[j] = (short)h;
            vl[j] = (short)f2bf(f - bf2f(h));
        }
        *(short8*)(ohi + ch * 8) = vh;
        *(short8*)(olo + ch * 8) = vl;
    }
}

// ---------------------------------------------------------------------------
// Kernel 3: fused Gram (bf16x2 MFMA) + count-sketch scatter, per 128x128 tile.
// Grid (NTP=10 tile-pairs bi<=bj, 32 batches), 256 threads = 4 waves.
// Wave w stages one of {Ahi,Alo,Bhi,Blo} and computes a 64x64 quadrant.
// Off-diagonal tiles scatter each element AND its transpose-mirror.
// Partial bins written to pbins[(b*NTP+tp)*PROJ].
// ---------------------------------------------------------------------------
__global__ __launch_bounds__(256) void gramscatter_kernel(
    const unsigned short* __restrict__ XThi, const unsigned short* __restrict__ XTlo,
    const int* __restrict__ h1, const float* __restrict__ s1,
    const int* __restrict__ h2, const float* __restrict__ s2,
    float* __restrict__ pbins)
{
    const int tp  = blockIdx.x;
    const int bat = blockIdx.y;
    const int bi  = (tp < 4) ? 0 : (tp < 7) ? 1 : (tp < 9) ? 2 : 3;
    const int bj  = (tp < 4) ? tp : (tp < 7) ? (tp - 3) : (tp < 9) ? (tp - 5) : 3;
    const int tid  = threadIdx.x;
    const int w    = tid >> 6;
    const int lane = tid & 63;

    __shared__ __align__(16) unsigned short Sbuf[4][4096];  // Ahi,Alo,Bhi,Blo 32 KB
    __shared__ float bins[PROJ];                            // 32 KB
    __shared__ int   th1[256]; __shared__ float ts1[256];
    __shared__ int   th2[256]; __shared__ float ts2[256];   // [0..127]=bi rows, [128..255]=bj cols

    for (int i = tid; i < PROJ; i += 256) bins[i] = 0.f;
    {
        const int g = (tid < 128) ? (bi * 128 + tid) : (bj * 128 + tid - 128);
        th1[tid] = h1[g]; ts1[tid] = s1[g];
        th2[tid] = h2[g]; ts2[tid] = s2[g];
    }

    const int tile = (w < 2) ? bi : bj;
    const unsigned short* srcbase = ((w & 1) ? XTlo : XThi)
                                  + (size_t)bat * NSLAB * 16384 + (size_t)tile * 4096;
    const int rowq = w >> 1, colq = w & 1;

    f32x4 acc[16];
#pragma unroll
    for (int i = 0; i < 16; ++i) { acc[i][0]=0.f; acc[i][1]=0.f; acc[i][2]=0.f; acc[i][3]=0.f; }

    __syncthreads();

    for (int ks = 0; ks < NSLAB; ++ks) {
        const unsigned short* src = srcbase + (size_t)ks * 16384;
#pragma unroll
        for (int i = 0; i < 8; ++i) {
            const int off = i * 512 + lane * 8;
            *(short8*)&Sbuf[w][off] = *(const short8*)(src + off);
        }
        __syncthreads();

        short8 ah[4], al[4], bh[4], bl[4];
#pragma unroll
        for (int t = 0; t < 4; ++t) {
            ah[t] = *(const short8*)&Sbuf[0][(rowq * 4 + t) * 512 + lane * 8];
            al[t] = *(const short8*)&Sbuf[1][(rowq * 4 + t) * 512 + lane * 8];
            bh[t] = *(const short8*)&Sbuf[2][(colq * 4 + t) * 512 + lane * 8];
            bl[t] = *(const short8*)&Sbuf[3][(colq * 4 + t) * 512 + lane * 8];
        }
#pragma unroll
        for (int mt = 0; mt < 4; ++mt)
#pragma unroll
            for (int nt = 0; nt < 4; ++nt) {
                const int idx = mt * 4 + nt;
                acc[idx] = __builtin_amdgcn_mfma_f32_16x16x32_bf16(ah[mt], bh[nt], acc[idx], 0, 0, 0);
                acc[idx] = __builtin_amdgcn_mfma_f32_16x16x32_bf16(ah[mt], bl[nt], acc[idx], 0, 0, 0);
                acc[idx] = __builtin_amdgcn_mfma_f32_16x16x32_bf16(al[mt], bh[nt], acc[idx], 0, 0, 0);
            }
        __syncthreads();
    }

    // ---- scatter: C/D layout col=lane&15, row=(lane>>4)*4+reg ----
    const bool mirror = (bi != bj);
    int   h2c[4], h1c[4];
    float s2c[4], s1c[4];
#pragma unroll
    for (int nt = 0; nt < 4; ++nt) {
        const int cl = colq * 64 + nt * 16 + (lane & 15);
        h2c[nt] = th2[128 + cl]; s2c[nt] = ts2[128 + cl];
        h1c[nt] = th1[128 + cl]; s1c[nt] = ts1[128 + cl];
    }
    const int quad = lane >> 4;
#pragma unroll
    for (int mt = 0; mt < 4; ++mt)
#pragma unroll
        for (int reg = 0; reg < 4; ++reg) {
            const int rl = rowq * 64 + mt * 16 + quad * 4 + reg;
            const int   h1r = th1[rl]; const float s1r = ts1[rl];
            const int   h2r = th2[rl]; const float s2r = ts2[rl];
#pragma unroll
            for (int nt = 0; nt < 4; ++nt) {
                const float v = acc[mt * 4 + nt][reg];
                atomicAdd(&bins[(h1r + h2c[nt]) & (PROJ - 1)], s1r * s2c[nt] * v);
                if (mirror)
                    atomicAdd(&bins[(h1c[nt] + h2r) & (PROJ - 1)], s1c[nt] * s2r * v);
            }
        }
    __syncthreads();

    float* dst = pbins + ((size_t)bat * NTP + tp) * PROJ;
    for (int i = tid * 4; i < PROJ; i += 1024)
        *(float4*)(dst + i) = *(const float4*)&bins[i];
}

// ---------------------------------------------------------------------------
// Kernel 4: reduce NTP partials per bin, signed sqrt, emit unnormalized y,
// accumulate per-batch sum |v| (== sum y^2). Grid (8, 32).
// ---------------------------------------------------------------------------
__global__ __launch_bounds__(256) void reduce_kernel(
    const float* __restrict__ pbins, float* __restrict__ out,
    float* __restrict__ norm)
{
    const int chunk = blockIdx.x;
    const int bat   = blockIdx.y;
    const int tid   = threadIdx.x;
    const int base  = chunk * 1024 + tid * 4;

    const float* pb = pbins + (size_t)bat * NTP * PROJ;
    float4 v = make_float4(0.f, 0.f, 0.f, 0.f);
#pragma unroll
    for (int t = 0; t < NTP; ++t) {
        float4 p = *(const float4*)(pb + (size_t)t * PROJ + base);
        v.x += p.x; v.y += p.y; v.z += p.z; v.w += p.w;
    }

    float4 sv;
    sv.x = (v.x >= 0.f) ? sqrtf(v.x) : -sqrtf(-v.x);
    sv.y = (v.y >= 0.f) ? sqrtf(v.y) : -sqrtf(-v.y);
    sv.z = (v.z >= 0.f) ? sqrtf(v.z) : -sqrtf(-v.z);
    sv.w = (v.w >= 0.f) ? sqrtf(v.w) : -sqrtf(-v.w);
    *(float4*)(out + (size_t)bat * PROJ + base) = sv;

    float local = fabsf(v.x) + fabsf(v.y) + fabsf(v.z) + fabsf(v.w);
#pragma unroll
    for (int off = 32; off > 0; off >>= 1) local += __shfl_down(local, off, 64);

    __shared__ float wred[4];
    if ((tid & 63) == 0) wred[tid >> 6] = local;
    __syncthreads();
    if (tid == 0)
        atomicAdd(&norm[bat], wred[0] + wred[1] + wred[2] + wred[3]);
}

// ---------------------------------------------------------------------------
// Kernel 5: scale by rsqrt(norm). Grid (8, 32).
// ---------------------------------------------------------------------------
__global__ __launch_bounds__(256) void normalize_kernel(
    float* __restrict__ out, const float* __restrict__ norm)
{
    const int bat = blockIdx.y;
    const int idx = blockIdx.x * 1024 + threadIdx.x * 4;
    const float inv = rsqrtf(fmaxf(norm[bat], 1e-10f));
    float4* p = (float4*)(out + (size_t)bat * PROJ + idx);
    float4 v = *p;
    v.x *= inv; v.y *= inv; v.z *= inv; v.w *= inv;
    *p = v;
}

// ---------------------------------------------------------------------------
extern "C" void kernel_launch(void* const* d_in, const int* in_sizes, int n_in,
                              void* d_out, int out_size, void* d_ws, size_t ws_size,
                              hipStream_t stream)
{
    const float* x  = (const float*)d_in[0];   // [32,14,14,512]
    const float* M1 = (const float*)d_in[1];   // [512,8192]
    const float* M2 = (const float*)d_in[2];   // [512,8192]
    float* out = (float*)d_out;                // [32,8192]

    char* ws = (char*)d_ws;
    int*            h1    = (int*)   (ws + 0);
    float*          s1    = (float*) (ws + 2048);
    int*            h2    = (int*)   (ws + 4096);
    float*          s2    = (float*) (ws + 6144);
    float*          norm  = (float*) (ws + 8192);
    unsigned short* XThi  = (unsigned short*)(ws + 16384);      // 7,340,032 B
    unsigned short* XTlo  = (unsigned short*)(ws + 7356416);    // 7,340,032 B
    float*          pbins = (float*) (ws + 14696448);           // 10,485,760 B
    // total ws use ~25.2 MB

    extract_kernel<<<dim3(512, 2), 256, 0, stream>>>(M1, M2, h1, s1, h2, s2, norm);
    prep_kernel<<<dim3(NSLAB, NBATCH), 256, 0, stream>>>(x, XThi, XTlo);
    gramscatter_kernel<<<dim3(NTP, NBATCH), 256, 0, stream>>>(XThi, XTlo, h1, s1, h2, s2, pbins);
    reduce_kernel<<<dim3(8, NBATCH), 256, 0, stream>>>(pbins, out, norm);
    normalize_kernel<<<dim3(8, NBATCH), 256, 0, stream>>>(out, norm);
}

// Round 4
// 185.189 us; speedup vs baseline: 1.0530x; 1.0530x over previous
//
#include <hip/hip_runtime.h>
#include <math.h>

#define PROJ 8192
#define CDIM 512
#define HWPOS 196
#define NBATCH 32
#define NSLAB 7             // K padded 196 -> 224 = 7 slabs of 32
#define NTP 10              // tile pairs bi<=bj over 4x4 grid of 128-col tiles

typedef __attribute__((ext_vector_type(8))) short   short8;
typedef __attribute__((ext_vector_type(4))) float   f32x4;

__device__ __forceinline__ unsigned short f2bf(float f) {
    unsigned u = __float_as_uint(f);
    u += 0x7fff + ((u >> 16) & 1);          // round-to-nearest-even
    return (unsigned short)(u >> 16);
}
__device__ __forceinline__ float bf2f(unsigned short h) {
    return __uint_as_float(((unsigned)h) << 16);
}

// ---------------------------------------------------------------------------
// Kernel 1: extract (h, s) from the dense sketch matrices + zero norm accum.
// ---------------------------------------------------------------------------
__global__ __launch_bounds__(256) void extract_kernel(
    const float* __restrict__ M1, const float* __restrict__ M2,
    int* __restrict__ h1, float* __restrict__ s1,
    int* __restrict__ h2, float* __restrict__ s2,
    float* __restrict__ norm)
{
    const int row = blockIdx.x;
    const float* M = blockIdx.y ? M2 : M1;
    int*   h = blockIdx.y ? h2 : h1;
    float* s = blockIdx.y ? s2 : s1;
    const float* mrow = M + (size_t)row * PROJ;

    if (blockIdx.x == 0 && blockIdx.y == 0 && threadIdx.x < NBATCH)
        norm[threadIdx.x] = 0.0f;

    for (int i = threadIdx.x * 4; i < PROJ; i += 256 * 4) {
        float4 v = *(const float4*)(mrow + i);
        if (v.x != 0.0f) { h[row] = i + 0; s[row] = v.x; }
        if (v.y != 0.0f) { h[row] = i + 1; s[row] = v.y; }
        if (v.z != 0.0f) { h[row] = i + 2; s[row] = v.z; }
        if (v.w != 0.0f) { h[row] = i + 3; s[row] = v.w; }
    }
}

// ---------------------------------------------------------------------------
// Kernel 2: prep — split fp32 x into bf16 hi/lo, transpose to fragment order.
// Output layout (ushort): [b][kslab(7)][cgrp(32)][quad(4)][c16(16)][j(8)]
// i.e. element (c = cgrp*16+c16, k = kslab*32+quad*8+j); k>=196 zero-padded.
// ---------------------------------------------------------------------------
__global__ __launch_bounds__(256) void prep_kernel(
    const float* __restrict__ x,
    unsigned short* __restrict__ XThi, unsigned short* __restrict__ XTlo)
{
    const int ks  = blockIdx.x;
    const int bat = blockIdx.y;
    const int tid = threadIdx.x;
    __shared__ float xt[32][513];            // +1 pad breaks bank conflicts

    const float* xb = x + (size_t)bat * HWPOS * CDIM;
    const int k0 = ks * 32;
#pragma unroll
    for (int i = 0; i < 16; ++i) {
        const int idx = i * 1024 + tid * 4;
        const int kr  = idx >> 9;
        const int c   = idx & 511;
        float4 v = make_float4(0.f, 0.f, 0.f, 0.f);
        if (k0 + kr < HWPOS) v = *(const float4*)(xb + (size_t)(k0 + kr) * CDIM + c);
        xt[kr][c+0] = v.x; xt[kr][c+1] = v.y; xt[kr][c+2] = v.z; xt[kr][c+3] = v.w;
    }
    __syncthreads();

    unsigned short* ohi = XThi + ((size_t)bat * NSLAB + ks) * 16384;
    unsigned short* olo = XTlo + ((size_t)bat * NSLAB + ks) * 16384;
#pragma unroll
    for (int i = 0; i < 8; ++i) {
        const int ch   = i * 256 + tid;      // chunk 0..2047, memory order
        const int c16  = ch & 15;
        const int quad = (ch >> 4) & 3;
        const int cgrp = ch >> 6;
        const int c    = cgrp * 16 + c16;
        short8 vh, vl;
#pragma unroll
        for (int j = 0; j < 8; ++j) {
            float f = xt[quad * 8 + j][c];
            unsigned short h = f2bf(f);
            vh[j] = (short)h;
            vl[j] = (short)f2bf(f - bf2f(h));
        }
        *(short8*)(ohi + ch * 8) = vh;
        *(short8*)(olo + ch * 8) = vl;
    }
}

// ---------------------------------------------------------------------------
// Kernel 3: fused Gram (bf16x2 MFMA) + count-sketch scatter, per 128x128 tile.
// Linear grid of 320 WGs, XCD-swizzled: id&7 == bat%8 so each batch's 10 WGs
// share one XCD's L2. 4 waves; wave w stages one of {Ahi,Alo,Bhi,Blo}.
// Async double-buffered staging via global_load_lds; scatter via ds_add_f32
// (unsafeAtomicAdd). Off-diagonal tiles also scatter the transpose-mirror.
// ---------------------------------------------------------------------------
__global__ __launch_bounds__(256) void gramscatter_kernel(
    const unsigned short* __restrict__ XThi, const unsigned short* __restrict__ XTlo,
    const int* __restrict__ h1, const float* __restrict__ s1,
    const int* __restrict__ h2, const float* __restrict__ s2,
    float* __restrict__ pbins)
{
    const int id  = blockIdx.x;             // 0..319
    const int sub = id >> 3;                // 0..39
    const int tp  = sub % NTP;
    const int bat = (id & 7) + 8 * (sub / NTP);
    const int bi  = (tp < 4) ? 0 : (tp < 7) ? 1 : (tp < 9) ? 2 : 3;
    const int bj  = (tp < 4) ? tp : (tp < 7) ? (tp - 3) : (tp < 9) ? (tp - 5) : 3;
    const int tid  = threadIdx.x;
    const int w    = tid >> 6;
    const int lane = tid & 63;

    __shared__ __align__(16) unsigned short Sbuf[2][4][4096]; // 64 KB double buf
    __shared__ float bins[PROJ];                              // 32 KB
    __shared__ int   th1[256]; __shared__ float ts1[256];
    __shared__ int   th2[256]; __shared__ float ts2[256];

    const int tile = (w < 2) ? bi : bj;
    const unsigned short* srcbase = ((w & 1) ? XTlo : XThi)
                                  + (size_t)bat * NSLAB * 16384 + (size_t)tile * 4096;
    const int rowq = w >> 1, colq = w & 1;

    // issue async prefetch of slab 0 (16B per lane, lds dest wave-uniform base)
    {
        const unsigned short* src = srcbase;
        unsigned short* dst = &Sbuf[0][w][0];
#pragma unroll
        for (int i = 0; i < 8; ++i)
            __builtin_amdgcn_global_load_lds(
                (const __attribute__((address_space(1))) void*)(src + i * 512 + lane * 8),
                (__attribute__((address_space(3))) void*)(dst + i * 512), 16, 0, 0);
    }

    // overlap: zero bins + load h/s tables while slab 0 is in flight
    for (int i = tid; i < PROJ; i += 256) bins[i] = 0.f;
    {
        const int g = (tid < 128) ? (bi * 128 + tid) : (bj * 128 + tid - 128);
        th1[tid] = h1[g]; ts1[tid] = s1[g];
        th2[tid] = h2[g]; ts2[tid] = s2[g];
    }

    f32x4 acc[16];
#pragma unroll
    for (int i = 0; i < 16; ++i) { acc[i][0]=0.f; acc[i][1]=0.f; acc[i][2]=0.f; acc[i][3]=0.f; }

    for (int ks = 0; ks < NSLAB; ++ks) {
        __syncthreads();                 // drains vmcnt -> slab ks resident
        const int buf = ks & 1;

        if (ks + 1 < NSLAB) {            // prefetch next slab into other buffer
            const unsigned short* src = srcbase + (size_t)(ks + 1) * 16384;
            unsigned short* dst = &Sbuf[buf ^ 1][w][0];
#pragma unroll
            for (int i = 0; i < 8; ++i)
                __builtin_amdgcn_global_load_lds(
                    (const __attribute__((address_space(1))) void*)(src + i * 512 + lane * 8),
                    (__attribute__((address_space(3))) void*)(dst + i * 512), 16, 0, 0);
        }

        short8 ah[4], al[4], bh[4], bl[4];
#pragma unroll
        for (int t = 0; t < 4; ++t) {
            ah[t] = *(const short8*)&Sbuf[buf][0][(rowq * 4 + t) * 512 + lane * 8];
            al[t] = *(const short8*)&Sbuf[buf][1][(rowq * 4 + t) * 512 + lane * 8];
            bh[t] = *(const short8*)&Sbuf[buf][2][(colq * 4 + t) * 512 + lane * 8];
            bl[t] = *(const short8*)&Sbuf[buf][3][(colq * 4 + t) * 512 + lane * 8];
        }
#pragma unroll
        for (int mt = 0; mt < 4; ++mt)
#pragma unroll
            for (int nt = 0; nt < 4; ++nt) {
                const int idx = mt * 4 + nt;
                acc[idx] = __builtin_amdgcn_mfma_f32_16x16x32_bf16(ah[mt], bh[nt], acc[idx], 0, 0, 0);
                acc[idx] = __builtin_amdgcn_mfma_f32_16x16x32_bf16(ah[mt], bl[nt], acc[idx], 0, 0, 0);
                acc[idx] = __builtin_amdgcn_mfma_f32_16x16x32_bf16(al[mt], bh[nt], acc[idx], 0, 0, 0);
            }
    }

    // ---- scatter: C/D layout col=lane&15, row=(lane>>4)*4+reg ----
    const bool mirror = (bi != bj);
    int   h2c[4], h1c[4];
    float s2c[4], s1c[4];
#pragma unroll
    for (int nt = 0; nt < 4; ++nt) {
        const int cl = colq * 64 + nt * 16 + (lane & 15);
        h2c[nt] = th2[128 + cl]; s2c[nt] = ts2[128 + cl];
        h1c[nt] = th1[128 + cl]; s1c[nt] = ts1[128 + cl];
    }
    const int quad = lane >> 4;
#pragma unroll
    for (int mt = 0; mt < 4; ++mt)
#pragma unroll
        for (int reg = 0; reg < 4; ++reg) {
            const int rl = rowq * 64 + mt * 16 + quad * 4 + reg;
            const int   h1r = th1[rl]; const float s1r = ts1[rl];
            const int   h2r = th2[rl]; const float s2r = ts2[rl];
#pragma unroll
            for (int nt = 0; nt < 4; ++nt) {
                const float v = acc[mt * 4 + nt][reg];
                unsafeAtomicAdd(&bins[(h1r + h2c[nt]) & (PROJ - 1)], s1r * s2c[nt] * v);
                if (mirror)
                    unsafeAtomicAdd(&bins[(h1c[nt] + h2r) & (PROJ - 1)], s1c[nt] * s2r * v);
            }
        }
    __syncthreads();

    float* dst = pbins + ((size_t)bat * NTP + tp) * PROJ;
    for (int i = tid * 4; i < PROJ; i += 1024)
        *(float4*)(dst + i) = *(const float4*)&bins[i];
}

// ---------------------------------------------------------------------------
// Kernel 4: reduce NTP partials per bin, signed sqrt, emit unnormalized y,
// accumulate per-batch sum |v| (== sum y^2). Grid (8, 32).
// ---------------------------------------------------------------------------
__global__ __launch_bounds__(256) void reduce_kernel(
    const float* __restrict__ pbins, float* __restrict__ out,
    float* __restrict__ norm)
{
    const int chunk = blockIdx.x;
    const int bat   = blockIdx.y;
    const int tid   = threadIdx.x;
    const int base  = chunk * 1024 + tid * 4;

    const float* pb = pbins + (size_t)bat * NTP * PROJ;
    float4 v = make_float4(0.f, 0.f, 0.f, 0.f);
#pragma unroll
    for (int t = 0; t < NTP; ++t) {
        float4 p = *(const float4*)(pb + (size_t)t * PROJ + base);
        v.x += p.x; v.y += p.y; v.z += p.z; v.w += p.w;
    }

    float4 sv;
    sv.x = (v.x >= 0.f) ? sqrtf(v.x) : -sqrtf(-v.x);
    sv.y = (v.y >= 0.f) ? sqrtf(v.y) : -sqrtf(-v.y);
    sv.z = (v.z >= 0.f) ? sqrtf(v.z) : -sqrtf(-v.z);
    sv.w = (v.w >= 0.f) ? sqrtf(v.w) : -sqrtf(-v.w);
    *(float4*)(out + (size_t)bat * PROJ + base) = sv;

    float local = fabsf(v.x) + fabsf(v.y) + fabsf(v.z) + fabsf(v.w);
#pragma unroll
    for (int off = 32; off > 0; off >>= 1) local += __shfl_down(local, off, 64);

    __shared__ float wred[4];
    if ((tid & 63) == 0) wred[tid >> 6] = local;
    __syncthreads();
    if (tid == 0)
        unsafeAtomicAdd(&norm[bat], wred[0] + wred[1] + wred[2] + wred[3]);
}

// ---------------------------------------------------------------------------
// Kernel 5: scale by rsqrt(norm). Grid (8, 32).
// ---------------------------------------------------------------------------
__global__ __launch_bounds__(256) void normalize_kernel(
    float* __restrict__ out, const float* __restrict__ norm)
{
    const int bat = blockIdx.y;
    const int idx = blockIdx.x * 1024 + threadIdx.x * 4;
    const float inv = rsqrtf(fmaxf(norm[bat], 1e-10f));
    float4* p = (float4*)(out + (size_t)bat * PROJ + idx);
    float4 v = *p;
    v.x *= inv; v.y *= inv; v.z *= inv; v.w *= inv;
    *p = v;
}

// ---------------------------------------------------------------------------
extern "C" void kernel_launch(void* const* d_in, const int* in_sizes, int n_in,
                              void* d_out, int out_size, void* d_ws, size_t ws_size,
                              hipStream_t stream)
{
    const float* x  = (const float*)d_in[0];   // [32,14,14,512]
    const float* M1 = (const float*)d_in[1];   // [512,8192]
    const float* M2 = (const float*)d_in[2];   // [512,8192]
    float* out = (float*)d_out;                // [32,8192]

    char* ws = (char*)d_ws;
    int*            h1    = (int*)   (ws + 0);
    float*          s1    = (float*) (ws + 2048);
    int*            h2    = (int*)   (ws + 4096);
    float*          s2    = (float*) (ws + 6144);
    float*          norm  = (float*) (ws + 8192);
    unsigned short* XThi  = (unsigned short*)(ws + 16384);      // 7,340,032 B
    unsigned short* XTlo  = (unsigned short*)(ws + 7356416);    // 7,340,032 B
    float*          pbins = (float*) (ws + 14696448);           // 10,485,760 B
    // total ws use ~25.2 MB

    extract_kernel<<<dim3(512, 2), 256, 0, stream>>>(M1, M2, h1, s1, h2, s2, norm);
    prep_kernel<<<dim3(NSLAB, NBATCH), 256, 0, stream>>>(x, XThi, XTlo);
    gramscatter_kernel<<<NTP * NBATCH, 256, 0, stream>>>(XThi, XTlo, h1, s1, h2, s2, pbins);
    reduce_kernel<<<dim3(8, NBATCH), 256, 0, stream>>>(pbins, out, norm);
    normalize_kernel<<<dim3(8, NBATCH), 256, 0, stream>>>(out, norm);
}

// Round 5
// 185.126 us; speedup vs baseline: 1.0534x; 1.0003x over previous
//
#include <hip/hip_runtime.h>
#include <math.h>

#define PROJ 8192
#define CDIM 512
#define HWPOS 196
#define NBATCH 32
#define NSLAB 7             // K padded 196 -> 224 = 7 slabs of 32
#define NTP 10              // tile pairs bi<=bj over 4x4 grid of 128-col tiles

typedef __attribute__((ext_vector_type(8))) short   short8;
typedef __attribute__((ext_vector_type(4))) float   f32x4;

__device__ __forceinline__ unsigned short f2bf(float f) {
    unsigned u = __float_as_uint(f);
    u += 0x7fff + ((u >> 16) & 1);          // round-to-nearest-even
    return (unsigned short)(u >> 16);
}
__device__ __forceinline__ float bf2f(unsigned short h) {
    return __uint_as_float(((unsigned)h) << 16);
}

// Native no-return LDS fp32 atomic add. unsafeAtomicAdd/atomicAdd on a
// generic pointer into LDS takes the safe CAS path (~400 cyc/op, the R4
// stall); ds_add_f32 is single-issue. lgkmcnt drained by __syncthreads().
__device__ __forceinline__ void lds_fadd(float* p, float v) {
    __attribute__((address_space(3))) float* lp =
        (__attribute__((address_space(3))) float*)p;
    asm volatile("ds_add_f32 %0, %1" : : "v"(lp), "v"(v) : "memory");
}

// ---------------------------------------------------------------------------
// Kernel 1: extract (h, s) from the dense sketch matrices + zero norm accum.
// ---------------------------------------------------------------------------
__global__ __launch_bounds__(256) void extract_kernel(
    const float* __restrict__ M1, const float* __restrict__ M2,
    int* __restrict__ h1, float* __restrict__ s1,
    int* __restrict__ h2, float* __restrict__ s2,
    float* __restrict__ norm)
{
    const int row = blockIdx.x;
    const float* M = blockIdx.y ? M2 : M1;
    int*   h = blockIdx.y ? h2 : h1;
    float* s = blockIdx.y ? s2 : s1;
    const float* mrow = M + (size_t)row * PROJ;

    if (blockIdx.x == 0 && blockIdx.y == 0 && threadIdx.x < NBATCH)
        norm[threadIdx.x] = 0.0f;

    for (int i = threadIdx.x * 4; i < PROJ; i += 256 * 4) {
        float4 v = *(const float4*)(mrow + i);
        if (v.x != 0.0f) { h[row] = i + 0; s[row] = v.x; }
        if (v.y != 0.0f) { h[row] = i + 1; s[row] = v.y; }
        if (v.z != 0.0f) { h[row] = i + 2; s[row] = v.z; }
        if (v.w != 0.0f) { h[row] = i + 3; s[row] = v.w; }
    }
}

// ---------------------------------------------------------------------------
// Kernel 2: prep — split fp32 x into bf16 hi/lo, transpose to fragment order.
// Output layout (ushort): [b][kslab(7)][cgrp(32)][quad(4)][c16(16)][j(8)]
// i.e. element (c = cgrp*16+c16, k = kslab*32+quad*8+j); k>=196 zero-padded.
// ---------------------------------------------------------------------------
__global__ __launch_bounds__(256) void prep_kernel(
    const float* __restrict__ x,
    unsigned short* __restrict__ XThi, unsigned short* __restrict__ XTlo)
{
    const int ks  = blockIdx.x;
    const int bat = blockIdx.y;
    const int tid = threadIdx.x;
    __shared__ float xt[32][513];            // +1 pad breaks bank conflicts

    const float* xb = x + (size_t)bat * HWPOS * CDIM;
    const int k0 = ks * 32;
#pragma unroll
    for (int i = 0; i < 16; ++i) {
        const int idx = i * 1024 + tid * 4;
        const int kr  = idx >> 9;
        const int c   = idx & 511;
        float4 v = make_float4(0.f, 0.f, 0.f, 0.f);
        if (k0 + kr < HWPOS) v = *(const float4*)(xb + (size_t)(k0 + kr) * CDIM + c);
        xt[kr][c+0] = v.x; xt[kr][c+1] = v.y; xt[kr][c+2] = v.z; xt[kr][c+3] = v.w;
    }
    __syncthreads();

    unsigned short* ohi = XThi + ((size_t)bat * NSLAB + ks) * 16384;
    unsigned short* olo = XTlo + ((size_t)bat * NSLAB + ks) * 16384;
#pragma unroll
    for (int i = 0; i < 8; ++i) {
        const int ch   = i * 256 + tid;      // chunk 0..2047, memory order
        const int c16  = ch & 15;
        const int quad = (ch >> 4) & 3;
        const int cgrp = ch >> 6;
        const int c    = cgrp * 16 + c16;
        short8 vh, vl;
#pragma unroll
        for (int j = 0; j < 8; ++j) {
            float f = xt[quad * 8 + j][c];
            unsigned short h = f2bf(f);
            vh[j] = (short)h;
            vl[j] = (short)f2bf(f - bf2f(h));
        }
        *(short8*)(ohi + ch * 8) = vh;
        *(short8*)(olo + ch * 8) = vl;
    }
}

// ---------------------------------------------------------------------------
// Kernel 3: fused Gram (bf16x2 MFMA) + count-sketch scatter, per 128x128 tile.
// Linear grid of 320 WGs, XCD-swizzled: id&7 == bat%8 so each batch's 10 WGs
// share one XCD's L2. 4 waves; wave w stages one of {Ahi,Alo,Bhi,Blo}.
// Async double-buffered staging via global_load_lds; scatter via native
// ds_add_f32. Off-diagonal tiles also scatter the transpose-mirror.
// ---------------------------------------------------------------------------
__global__ __launch_bounds__(256) void gramscatter_kernel(
    const unsigned short* __restrict__ XThi, const unsigned short* __restrict__ XTlo,
    const int* __restrict__ h1, const float* __restrict__ s1,
    const int* __restrict__ h2, const float* __restrict__ s2,
    float* __restrict__ pbins)
{
    const int id  = blockIdx.x;             // 0..319
    const int sub = id >> 3;                // 0..39
    const int tp  = sub % NTP;
    const int bat = (id & 7) + 8 * (sub / NTP);
    const int bi  = (tp < 4) ? 0 : (tp < 7) ? 1 : (tp < 9) ? 2 : 3;
    const int bj  = (tp < 4) ? tp : (tp < 7) ? (tp - 3) : (tp < 9) ? (tp - 5) : 3;
    const int tid  = threadIdx.x;
    const int w    = tid >> 6;
    const int lane = tid & 63;

    __shared__ __align__(16) unsigned short Sbuf[2][4][4096]; // 64 KB double buf
    __shared__ float bins[PROJ];                              // 32 KB
    __shared__ int   th1[256]; __shared__ float ts1[256];
    __shared__ int   th2[256]; __shared__ float ts2[256];

    const int tile = (w < 2) ? bi : bj;
    const unsigned short* srcbase = ((w & 1) ? XTlo : XThi)
                                  + (size_t)bat * NSLAB * 16384 + (size_t)tile * 4096;
    const int rowq = w >> 1, colq = w & 1;

    // issue async prefetch of slab 0 (16B per lane, lds dest wave-uniform base)
    {
        const unsigned short* src = srcbase;
        unsigned short* dst = &Sbuf[0][w][0];
#pragma unroll
        for (int i = 0; i < 8; ++i)
            __builtin_amdgcn_global_load_lds(
                (const __attribute__((address_space(1))) void*)(src + i * 512 + lane * 8),
                (__attribute__((address_space(3))) void*)(dst + i * 512), 16, 0, 0);
    }

    // overlap: zero bins + load h/s tables while slab 0 is in flight
    for (int i = tid; i < PROJ; i += 256) bins[i] = 0.f;
    {
        const int g = (tid < 128) ? (bi * 128 + tid) : (bj * 128 + tid - 128);
        th1[tid] = h1[g]; ts1[tid] = s1[g];
        th2[tid] = h2[g]; ts2[tid] = s2[g];
    }

    f32x4 acc[16];
#pragma unroll
    for (int i = 0; i < 16; ++i) { acc[i][0]=0.f; acc[i][1]=0.f; acc[i][2]=0.f; acc[i][3]=0.f; }

    for (int ks = 0; ks < NSLAB; ++ks) {
        __syncthreads();                 // drains vmcnt -> slab ks resident
        const int buf = ks & 1;

        if (ks + 1 < NSLAB) {            // prefetch next slab into other buffer
            const unsigned short* src = srcbase + (size_t)(ks + 1) * 16384;
            unsigned short* dst = &Sbuf[buf ^ 1][w][0];
#pragma unroll
            for (int i = 0; i < 8; ++i)
                __builtin_amdgcn_global_load_lds(
                    (const __attribute__((address_space(1))) void*)(src + i * 512 + lane * 8),
                    (__attribute__((address_space(3))) void*)(dst + i * 512), 16, 0, 0);
        }

        short8 ah[4], al[4], bh[4], bl[4];
#pragma unroll
        for (int t = 0; t < 4; ++t) {
            ah[t] = *(const short8*)&Sbuf[buf][0][(rowq * 4 + t) * 512 + lane * 8];
            al[t] = *(const short8*)&Sbuf[buf][1][(rowq * 4 + t) * 512 + lane * 8];
            bh[t] = *(const short8*)&Sbuf[buf][2][(colq * 4 + t) * 512 + lane * 8];
            bl[t] = *(const short8*)&Sbuf[buf][3][(colq * 4 + t) * 512 + lane * 8];
        }
#pragma unroll
        for (int mt = 0; mt < 4; ++mt)
#pragma unroll
            for (int nt = 0; nt < 4; ++nt) {
                const int idx = mt * 4 + nt;
                acc[idx] = __builtin_amdgcn_mfma_f32_16x16x32_bf16(ah[mt], bh[nt], acc[idx], 0, 0, 0);
                acc[idx] = __builtin_amdgcn_mfma_f32_16x16x32_bf16(ah[mt], bl[nt], acc[idx], 0, 0, 0);
                acc[idx] = __builtin_amdgcn_mfma_f32_16x16x32_bf16(al[mt], bh[nt], acc[idx], 0, 0, 0);
            }
    }

    // ---- scatter: C/D layout col=lane&15, row=(lane>>4)*4+reg ----
    const bool mirror = (bi != bj);
    int   h2c[4], h1c[4];
    float s2c[4], s1c[4];
#pragma unroll
    for (int nt = 0; nt < 4; ++nt) {
        const int cl = colq * 64 + nt * 16 + (lane & 15);
        h2c[nt] = th2[128 + cl]; s2c[nt] = ts2[128 + cl];
        h1c[nt] = th1[128 + cl]; s1c[nt] = ts1[128 + cl];
    }
    const int quad = lane >> 4;
#pragma unroll
    for (int mt = 0; mt < 4; ++mt)
#pragma unroll
        for (int reg = 0; reg < 4; ++reg) {
            const int rl = rowq * 64 + mt * 16 + quad * 4 + reg;
            const int   h1r = th1[rl]; const float s1r = ts1[rl];
            const int   h2r = th2[rl]; const float s2r = ts2[rl];
#pragma unroll
            for (int nt = 0; nt < 4; ++nt) {
                const float v = acc[mt * 4 + nt][reg];
                lds_fadd(&bins[(h1r + h2c[nt]) & (PROJ - 1)], s1r * s2c[nt] * v);
                if (mirror)
                    lds_fadd(&bins[(h1c[nt] + h2r) & (PROJ - 1)], s1c[nt] * s2r * v);
            }
        }
    __syncthreads();   // lgkmcnt(0) drain covers the ds_add_f32 ops

    float* dst = pbins + ((size_t)bat * NTP + tp) * PROJ;
    for (int i = tid * 4; i < PROJ; i += 1024)
        *(float4*)(dst + i) = *(const float4*)&bins[i];
}

// ---------------------------------------------------------------------------
// Kernel 4: reduce NTP partials per bin, signed sqrt, emit unnormalized y,
// accumulate per-batch sum |v| (== sum y^2). Grid (8, 32).
// ---------------------------------------------------------------------------
__global__ __launch_bounds__(256) void reduce_kernel(
    const float* __restrict__ pbins, float* __restrict__ out,
    float* __restrict__ norm)
{
    const int chunk = blockIdx.x;
    const int bat   = blockIdx.y;
    const int tid   = threadIdx.x;
    const int base  = chunk * 1024 + tid * 4;

    const float* pb = pbins + (size_t)bat * NTP * PROJ;
    float4 v = make_float4(0.f, 0.f, 0.f, 0.f);
#pragma unroll
    for (int t = 0; t < NTP; ++t) {
        float4 p = *(const float4*)(pb + (size_t)t * PROJ + base);
        v.x += p.x; v.y += p.y; v.z += p.z; v.w += p.w;
    }

    float4 sv;
    sv.x = (v.x >= 0.f) ? sqrtf(v.x) : -sqrtf(-v.x);
    sv.y = (v.y >= 0.f) ? sqrtf(v.y) : -sqrtf(-v.y);
    sv.z = (v.z >= 0.f) ? sqrtf(v.z) : -sqrtf(-v.z);
    sv.w = (v.w >= 0.f) ? sqrtf(v.w) : -sqrtf(-v.w);
    *(float4*)(out + (size_t)bat * PROJ + base) = sv;

    float local = fabsf(v.x) + fabsf(v.y) + fabsf(v.z) + fabsf(v.w);
#pragma unroll
    for (int off = 32; off > 0; off >>= 1) local += __shfl_down(local, off, 64);

    __shared__ float wred[4];
    if ((tid & 63) == 0) wred[tid >> 6] = local;
    __syncthreads();
    if (tid == 0)
        unsafeAtomicAdd(&norm[bat], wred[0] + wred[1] + wred[2] + wred[3]);
}

// ---------------------------------------------------------------------------
// Kernel 5: scale by rsqrt(norm). Grid (8, 32).
// ---------------------------------------------------------------------------
__global__ __launch_bounds__(256) void normalize_kernel(
    float* __restrict__ out, const float* __restrict__ norm)
{
    const int bat = blockIdx.y;
    const int idx = blockIdx.x * 1024 + threadIdx.x * 4;
    const float inv = rsqrtf(fmaxf(norm[bat], 1e-10f));
    float4* p = (float4*)(out + (size_t)bat * PROJ + idx);
    float4 v = *p;
    v.x *= inv; v.y *= inv; v.z *= inv; v.w *= inv;
    *p = v;
}

// ---------------------------------------------------------------------------
extern "C" void kernel_launch(void* const* d_in, const int* in_sizes, int n_in,
                              void* d_out, int out_size, void* d_ws, size_t ws_size,
                              hipStream_t stream)
{
    const float* x  = (const float*)d_in[0];   // [32,14,14,512]
    const float* M1 = (const float*)d_in[1];   // [512,8192]
    const float* M2 = (const float*)d_in[2];   // [512,8192]
    float* out = (float*)d_out;                // [32,8192]

    char* ws = (char*)d_ws;
    int*            h1    = (int*)   (ws + 0);
    float*          s1    = (float*) (ws + 2048);
    int*            h2    = (int*)   (ws + 4096);
    float*          s2    = (float*) (ws + 6144);
    float*          norm  = (float*) (ws + 8192);
    unsigned short* XThi  = (unsigned short*)(ws + 16384);      // 7,340,032 B
    unsigned short* XTlo  = (unsigned short*)(ws + 7356416);    // 7,340,032 B
    float*          pbins = (float*) (ws + 14696448);           // 10,485,760 B
    // total ws use ~25.2 MB

    extract_kernel<<<dim3(512, 2), 256, 0, stream>>>(M1, M2, h1, s1, h2, s2, norm);
    prep_kernel<<<dim3(NSLAB, NBATCH), 256, 0, stream>>>(x, XThi, XTlo);
    gramscatter_kernel<<<NTP * NBATCH, 256, 0, stream>>>(XThi, XTlo, h1, s1, h2, s2, pbins);
    reduce_kernel<<<dim3(8, NBATCH), 256, 0, stream>>>(pbins, out, norm);
    normalize_kernel<<<dim3(8, NBATCH), 256, 0, stream>>>(out, norm);
}